// Round 11
// baseline (625.324 us; speedup 1.0000x reference)
//
#include <hip/hip_runtime.h>
#include <hip/hip_bf16.h>
#include <math.h>

// Sizes (fixed by the problem)
#define T_STEPS 1024
#define B_SZ 32
#define F_SZ 2048
#define H_SZ 64
#define G4 256      // 4*H
#define C_SZ 101

typedef __bf16 bf16x8 __attribute__((ext_vector_type(8)));
typedef unsigned short u16x8 __attribute__((ext_vector_type(8)));
typedef unsigned short u16x4 __attribute__((ext_vector_type(4)));
typedef float f32x4 __attribute__((ext_vector_type(4)));
typedef float f32x2 __attribute__((ext_vector_type(2)));
typedef _Float16 f16x4 __attribute__((ext_vector_type(4)));

// Round-to-nearest-even fp32 -> bf16 split: f ~= hi + lo (each bf16).
__device__ __forceinline__ void split_bf16(float f, unsigned short& h,
                                           unsigned short& l) {
  unsigned u = __builtin_bit_cast(unsigned, f);
  unsigned rh = (u + 0x7FFFu + ((u >> 16) & 1u)) >> 16;
  h = (unsigned short)rh;
  float d = f - __builtin_bit_cast(float, rh << 16);
  unsigned ud = __builtin_bit_cast(unsigned, d);
  l = (unsigned short)((ud + 0x7FFFu + ((ud >> 16) & 1u)) >> 16);
}

// v_dot2_f32_f16: d = a.x*b.x + a.y*b.y + c (f16 inputs, fp32 accumulate).
// Operands typed as float (each holds a packed f16x2).
__device__ __forceinline__ float dot2(float a, float b, float c) {
  float d;
  asm("v_dot2_f32_f16 %0, %1, %2, %3" : "=v"(d) : "v"(a), "v"(b), "v"(c));
  return d;
}

__device__ __forceinline__ float sigm_f(float x) {
  return __builtin_amdgcn_rcpf(1.f + __expf(-x));
}
__device__ __forceinline__ float tanh_f(float x) {
  return 2.f * __builtin_amdgcn_rcpf(1.f + __expf(-2.f * x)) - 1.f;
}

#define REP8(M) M(0) M(1) M(2) M(3) M(4) M(5) M(6) M(7)
#define REP16(M) M(0) M(1) M(2) M(3) M(4) M(5) M(6) M(7) \
                 M(8) M(9) M(10) M(11) M(12) M(13) M(14) M(15)

// ---------------------------------------------------------------------------
// Phase 0a: pre-split W_ih into bf16 hi/lo ONCE.
// ---------------------------------------------------------------------------
__global__ __launch_bounds__(256) void presplit_w(
    const float* __restrict__ W, unsigned short* __restrict__ hi,
    unsigned short* __restrict__ lo) {
  const int idx = (blockIdx.x * 256 + threadIdx.x) * 4;
  float4 v = *(const float4*)(W + idx);
  unsigned short h0, l0, h1, l1, h2, l2, h3, l3;
  split_bf16(v.x, h0, l0);
  split_bf16(v.y, h1, l1);
  split_bf16(v.z, h2, l2);
  split_bf16(v.w, h3, l3);
  *(u16x4*)(hi + idx) = u16x4{h0, h1, h2, h3};
  *(u16x4*)(lo + idx) = u16x4{l0, l1, l2, l3};
}

// ---------------------------------------------------------------------------
// Phase 0b: W_hh fp32 -> f16 (16384 values; 16 blocks x 256 threads x 4).
// ---------------------------------------------------------------------------
__global__ __launch_bounds__(256) void whh_to_f16(
    const float* __restrict__ W, _Float16* __restrict__ o) {
  const int idx = (blockIdx.x * 256 + threadIdx.x) * 4;
  float4 v = *(const float4*)(W + idx);
  f16x4 r = {(_Float16)v.x, (_Float16)v.y, (_Float16)v.z, (_Float16)v.w};
  *(f16x4*)(o + idx) = r;
}

// ---------------------------------------------------------------------------
// Phase 1 (MFMA): xproj[t,b,j] = sum_f x[t,b,f]*W_ih[j,f] + b_ih[j] + b_hh[j]
// 128x256 tile, 8 waves, bf16-split 3-MFMA, BK=32; W pre-split from ws.
// ---------------------------------------------------------------------------
#define BM 128
#define BK 32
#define LDSP 40  // padded row stride in ushorts

__global__ __launch_bounds__(512) void xproj_mfma(
    const float* __restrict__ x, const unsigned short* __restrict__ Whi_g,
    const unsigned short* __restrict__ Wlo_g, const float* __restrict__ b_ih,
    const float* __restrict__ b_hh, float* __restrict__ xproj) {
  __shared__ alignas(16) unsigned short Xhi[BM][LDSP];
  __shared__ alignas(16) unsigned short Xlo[BM][LDSP];
  __shared__ alignas(16) unsigned short Whi[G4][LDSP];
  __shared__ alignas(16) unsigned short Wlo[G4][LDSP];

  const int tid = threadIdx.x;
  const int lane = tid & 63;
  const int wave = tid >> 6;  // 0..7
  const int wm = wave >> 2;   // 0..1 (M)
  const int wn = wave & 3;    // 0..3 (N)
  const size_t R0 = (size_t)blockIdx.x * BM;

  const int xr = tid >> 2;
  const int xs = (tid & 3) * 8;
  const int wr = tid >> 1;
  const int wsg = (tid & 1) * 16;

  const float* xbase = x + (R0 + xr) * (size_t)F_SZ + xs;
  const unsigned short* whb = Whi_g + (size_t)wr * F_SZ + wsg;
  const unsigned short* wlb = Wlo_g + (size_t)wr * F_SZ + wsg;

  float4 xa = *(const float4*)(xbase + 0);
  float4 xb = *(const float4*)(xbase + 4);
  u16x8 wh0 = *(const u16x8*)(whb + 0);
  u16x8 wh1 = *(const u16x8*)(whb + 8);
  u16x8 wl0 = *(const u16x8*)(wlb + 0);
  u16x8 wl1 = *(const u16x8*)(wlb + 8);

  f32x4 acc[4][4] = {};

  const int ar = lane & 15;
  const int ak = (lane >> 4) * 8;

  for (int kt = 0; kt < F_SZ; kt += BK) {
    {
      float xf[8] = {xa.x, xa.y, xa.z, xa.w, xb.x, xb.y, xb.z, xb.w};
      u16x8 xh, xl;
#pragma unroll
      for (int i = 0; i < 8; ++i) {
        unsigned short h, l;
        split_bf16(xf[i], h, l);
        xh[i] = h;
        xl[i] = l;
      }
      *(u16x8*)&Xhi[xr][xs] = xh;
      *(u16x8*)&Xlo[xr][xs] = xl;
      *(u16x8*)&Whi[wr][wsg] = wh0;
      *(u16x8*)&Whi[wr][wsg + 8] = wh1;
      *(u16x8*)&Wlo[wr][wsg] = wl0;
      *(u16x8*)&Wlo[wr][wsg + 8] = wl1;
    }
    __syncthreads();

    const int ktn = (kt + BK < F_SZ) ? kt + BK : kt;
    xa = *(const float4*)(xbase + ktn + 0);
    xb = *(const float4*)(xbase + ktn + 4);
    wh0 = *(const u16x8*)(whb + ktn + 0);
    wh1 = *(const u16x8*)(whb + ktn + 8);
    wl0 = *(const u16x8*)(wlb + ktn + 0);
    wl1 = *(const u16x8*)(wlb + ktn + 8);

    bf16x8 Ah[4], Al[4], Bh[4], Bl[4];
#pragma unroll
    for (int fm = 0; fm < 4; ++fm) {
      const int row = wm * 64 + fm * 16 + ar;
      Ah[fm] = __builtin_bit_cast(bf16x8, *(const u16x8*)&Xhi[row][ak]);
      Al[fm] = __builtin_bit_cast(bf16x8, *(const u16x8*)&Xlo[row][ak]);
    }
#pragma unroll
    for (int fn = 0; fn < 4; ++fn) {
      const int col = wn * 64 + fn * 16 + ar;
      Bh[fn] = __builtin_bit_cast(bf16x8, *(const u16x8*)&Whi[col][ak]);
      Bl[fn] = __builtin_bit_cast(bf16x8, *(const u16x8*)&Wlo[col][ak]);
    }
#pragma unroll
    for (int fm = 0; fm < 4; ++fm) {
#pragma unroll
      for (int fn = 0; fn < 4; ++fn) {
        acc[fm][fn] = __builtin_amdgcn_mfma_f32_16x16x32_bf16(
            Ah[fm], Bh[fn], acc[fm][fn], 0, 0, 0);
        acc[fm][fn] = __builtin_amdgcn_mfma_f32_16x16x32_bf16(
            Ah[fm], Bl[fn], acc[fm][fn], 0, 0, 0);
        acc[fm][fn] = __builtin_amdgcn_mfma_f32_16x16x32_bf16(
            Al[fm], Bh[fn], acc[fm][fn], 0, 0, 0);
      }
    }
    __syncthreads();
  }

  const int cr = (lane >> 4) * 4;
  const int cc = lane & 15;
#pragma unroll
  for (int fn = 0; fn < 4; ++fn) {
    const int gj = wn * 64 + fn * 16 + cc;
    const float bias = b_ih[gj] + b_hh[gj];
#pragma unroll
    for (int fm = 0; fm < 4; ++fm) {
      const size_t gr = R0 + wm * 64 + fm * 16 + cr;
#pragma unroll
      for (int r = 0; r < 4; ++r) {
        xproj[(gr + r) * G4 + gj] = acc[fm][fn][r] + bias;
      }
    }
  }
}

// ---------------------------------------------------------------------------
// Phase 2: LSTM scan, ONE WAVE PER BATCH, ZERO BARRIERS, f16 weights.
// WHY: R7/R8/R10 (2-4 waves, different exchange schemes) all sit at ~1030
// cyc/step — the invariant is the cross-wave act/h exchange latency
// (write -> lgkmcnt -> s_barrier -> read ~= 290cyc) plus duplicated work.
// One wave kills the barrier AND the exchange: lane u owns unit u fully.
// Register math: 4 gate rows x 64 = 256 f16 = 128 VGPRs (fp32 version = 256
// VGPRs = R9's RA abort). Dot = 128 v_dot2_f32_f16 (2 MAC/instr, fp32 acc).
// h: parity LDS buffer in f16 — 1 ds_write_b16/lane, 8 uniform ds_read_b128;
// single-wave lockstep => lgkmcnt ordering only, NO s_barrier anywhere.
// Pinning: asm volatile loads + waves_per_eu(1,1) (R10-proven, same 32-quad
// count). Precision: W|h| < 1, f16 rel 5e-4 -> pre err ~1e-4 << 2.2e-3.
// ---------------------------------------------------------------------------
__global__ __attribute__((amdgpu_flat_work_group_size(64, 64)))
__attribute__((amdgpu_waves_per_eu(1, 1))) void lstm_scan_f16(
    const float* __restrict__ xproj, const _Float16* __restrict__ Whh16,
    float* __restrict__ hT) {
  const int b = blockIdx.x;   // 0..31
  const int u = threadIdx.x;  // 0..63

  __shared__ alignas(16) _Float16 hbuf[2][H_SZ];

  // --- pin 4 gate rows (f16): 4 x 8 dwordx4 = 32 quads = 128 VGPRs ---
  const _Float16* wp = Whh16 + (size_t)u * H_SZ;  // gate g row at +g*4096
#define PINW(i)                                                               \
  f32x4 w0_##i, w1_##i, w2_##i, w3_##i;                                       \
  {                                                                           \
    const _Float16* a0 = wp + 0 * 4096 + 8 * (i);                             \
    const _Float16* a1 = wp + 1 * 4096 + 8 * (i);                             \
    const _Float16* a2 = wp + 2 * 4096 + 8 * (i);                             \
    const _Float16* a3 = wp + 3 * 4096 + 8 * (i);                             \
    asm volatile("global_load_dwordx4 %0, %1, off" : "=v"(w0_##i) : "v"(a0)); \
    asm volatile("global_load_dwordx4 %0, %1, off" : "=v"(w1_##i) : "v"(a1)); \
    asm volatile("global_load_dwordx4 %0, %1, off" : "=v"(w2_##i) : "v"(a2)); \
    asm volatile("global_load_dwordx4 %0, %1, off" : "=v"(w3_##i) : "v"(a3)); \
  }
  REP8(PINW)
#undef PINW
  asm volatile("s_waitcnt vmcnt(0)" ::: "memory");

  hbuf[0][u] = (_Float16)0.f;
  float c = 0.f, hval = 0.f;
  int p = 0;

  const float* xpb = xproj + (size_t)b * G4 + u;  // stride per t: B*G4
  // 2-deep x prefetch (4 gate values per step)
  float xi0 = xpb[0], xf0 = xpb[64], xg0 = xpb[128], xo0 = xpb[192];
  const float* xp1 = xpb + (size_t)(B_SZ * G4);
  float xi1 = xp1[0], xf1 = xp1[64], xg1 = xp1[128], xo1 = xp1[192];

  for (int t = 0; t < T_STEPS; ++t) {
    const int tpre = (t + 2 < T_STEPS) ? t + 2 : t;
    const float* xp2 = xpb + (size_t)tpre * (B_SZ * G4);
    const float xi2 = xp2[0], xf2 = xp2[64], xg2 = xp2[128], xo2 = xp2[192];

    // h broadcast: 8 uniform ds_read_b128 (64 f16 = 32 packed pairs)
#define LH(i) const f32x4 hq_##i = *(const f32x4*)&hbuf[p][8 * (i)];
    REP8(LH)
#undef LH

    // 4 gate dots: 128 v_dot2_f32_f16 in 8 chains (16 deep each)
    float aiA = 0.f, aiB = 0.f, afA = 0.f, afB = 0.f;
    float agA = 0.f, agB = 0.f, aoA = 0.f, aoB = 0.f;
#define DOTQ(acc, i, wg)                         \
    acc = dot2(hq_##i[0], wg##_##i[0], acc);     \
    acc = dot2(hq_##i[1], wg##_##i[1], acc);     \
    acc = dot2(hq_##i[2], wg##_##i[2], acc);     \
    acc = dot2(hq_##i[3], wg##_##i[3], acc);
    DOTQ(aiA, 0, w0) DOTQ(aiA, 1, w0) DOTQ(aiA, 2, w0) DOTQ(aiA, 3, w0)
    DOTQ(aiB, 4, w0) DOTQ(aiB, 5, w0) DOTQ(aiB, 6, w0) DOTQ(aiB, 7, w0)
    DOTQ(afA, 0, w1) DOTQ(afA, 1, w1) DOTQ(afA, 2, w1) DOTQ(afA, 3, w1)
    DOTQ(afB, 4, w1) DOTQ(afB, 5, w1) DOTQ(afB, 6, w1) DOTQ(afB, 7, w1)
    DOTQ(agA, 0, w2) DOTQ(agA, 1, w2) DOTQ(agA, 2, w2) DOTQ(agA, 3, w2)
    DOTQ(agB, 4, w2) DOTQ(agB, 5, w2) DOTQ(agB, 6, w2) DOTQ(agB, 7, w2)
    DOTQ(aoA, 0, w3) DOTQ(aoA, 1, w3) DOTQ(aoA, 2, w3) DOTQ(aoA, 3, w3)
    DOTQ(aoB, 4, w3) DOTQ(aoB, 5, w3) DOTQ(aoB, 6, w3) DOTQ(aoB, 7, w3)
#undef DOTQ

    const float pi = xi0 + (aiA + aiB);
    const float pf = xf0 + (afA + afB);
    const float pg = xg0 + (agA + agB);
    const float po = xo0 + (aoA + aoB);

    // all gates fully in-lane; c in register; no exchange, no barrier
    c = sigm_f(pf) * c + sigm_f(pi) * tanh_f(pg);
    hval = sigm_f(po) * tanh_f(c);
    hbuf[p ^ 1][u] = (_Float16)hval;  // same-wave lockstep + lgkmcnt ordering
    p ^= 1;

    xi0 = xi1; xf0 = xf1; xg0 = xg1; xo0 = xo1;
    xi1 = xi2; xf1 = xf2; xg1 = xg2; xo1 = xo2;
  }

  hT[b * H_SZ + u] = hval;
}

// ---------------------------------------------------------------------------
// Phase 3: out[b][c] = sum_k hT[b][k] * W_lin[c][k] + b_lin[c]
// ---------------------------------------------------------------------------
__global__ __launch_bounds__(128) void final_linear_kernel(
    const float* __restrict__ hT, const float* __restrict__ W_lin,
    const float* __restrict__ b_lin, float* __restrict__ out) {
  const int b = blockIdx.x;
  const int cc = threadIdx.x;

  __shared__ float h_l[H_SZ];
  if (threadIdx.x < H_SZ) h_l[threadIdx.x] = hT[b * H_SZ + threadIdx.x];
  __syncthreads();

  if (cc < C_SZ) {
    float acc = b_lin[cc];
    const float* wr = W_lin + (size_t)cc * H_SZ;
#pragma unroll
    for (int k = 0; k < H_SZ; ++k) acc += h_l[k] * wr[k];
    out[b * C_SZ + cc] = acc;
  }
}

// ---------------------------------------------------------------------------
extern "C" void kernel_launch(void* const* d_in, const int* in_sizes, int n_in,
                              void* d_out, int out_size, void* d_ws,
                              size_t ws_size, hipStream_t stream) {
  const float* x = (const float*)d_in[0];      // [T,B,F]
  const float* W_ih = (const float*)d_in[1];   // [4H,F]
  const float* W_hh = (const float*)d_in[2];   // [4H,H]
  const float* b_ih = (const float*)d_in[3];   // [4H]
  const float* b_hh = (const float*)d_in[4];   // [4H]
  const float* W_lin = (const float*)d_in[5];  // [C,H]
  const float* b_lin = (const float*)d_in[6];  // [C]
  float* out = (float*)d_out;                  // [B,C]

  // ws layout: xproj 32MB | hT 8KB | Whi 1MB | Wlo 1MB | Whh_f16 32KB
  const size_t XP_BYTES = (size_t)T_STEPS * B_SZ * G4 * sizeof(float);
  float* xproj = (float*)d_ws;
  float* hT = (float*)((char*)d_ws + XP_BYTES);
  unsigned short* Whi_g = (unsigned short*)((char*)d_ws + XP_BYTES + 8192);
  unsigned short* Wlo_g = Whi_g + (size_t)G4 * F_SZ;
  _Float16* Whh16 = (_Float16*)(Wlo_g + (size_t)G4 * F_SZ);

  presplit_w<<<512, 256, 0, stream>>>(W_ih, Whi_g, Wlo_g);
  whh_to_f16<<<16, 256, 0, stream>>>(W_hh, Whh16);
  xproj_mfma<<<(T_STEPS * B_SZ) / BM, 512, 0, stream>>>(x, Whi_g, Wlo_g, b_ih,
                                                        b_hh, xproj);
  lstm_scan_f16<<<B_SZ, 64, 0, stream>>>(xproj, Whh16, hT);
  final_linear_kernel<<<B_SZ, 128, 0, stream>>>(hT, W_lin, b_lin, out);
}

// Round 13
// 553.048 us; speedup vs baseline: 1.1307x; 1.1307x over previous
//
#include <hip/hip_runtime.h>
#include <hip/hip_bf16.h>
#include <math.h>

// Sizes (fixed by the problem)
#define T_STEPS 1024
#define B_SZ 32
#define F_SZ 2048
#define H_SZ 64
#define G4 256      // 4*H
#define C_SZ 101

typedef __bf16 bf16x8 __attribute__((ext_vector_type(8)));
typedef unsigned short u16x8 __attribute__((ext_vector_type(8)));
typedef unsigned short u16x4 __attribute__((ext_vector_type(4)));
typedef float f32x4 __attribute__((ext_vector_type(4)));
typedef float f32x2 __attribute__((ext_vector_type(2)));
typedef _Float16 f16x4 __attribute__((ext_vector_type(4)));

// Round-to-nearest-even fp32 -> bf16 split: f ~= hi + lo (each bf16).
__device__ __forceinline__ void split_bf16(float f, unsigned short& h,
                                           unsigned short& l) {
  unsigned u = __builtin_bit_cast(unsigned, f);
  unsigned rh = (u + 0x7FFFu + ((u >> 16) & 1u)) >> 16;
  h = (unsigned short)rh;
  float d = f - __builtin_bit_cast(float, rh << 16);
  unsigned ud = __builtin_bit_cast(unsigned, d);
  l = (unsigned short)((ud + 0x7FFFu + ((ud >> 16) & 1u)) >> 16);
}

// v_dot2_f32_f16: d = a.x*b.x + a.y*b.y + c (f16 inputs, fp32 accumulate).
__device__ __forceinline__ float dot2(float a, float b, float c) {
  float d;
  asm("v_dot2_f32_f16 %0, %1, %2, %3" : "=v"(d) : "v"(a), "v"(b), "v"(c));
  return d;
}

__device__ __forceinline__ float sigm_f(float x) {
  return __builtin_amdgcn_rcpf(1.f + __expf(-x));
}
__device__ __forceinline__ float tanh_f(float x) {
  return 2.f * __builtin_amdgcn_rcpf(1.f + __expf(-2.f * x)) - 1.f;
}

#define REP8(M) M(0) M(1) M(2) M(3) M(4) M(5) M(6) M(7)

// ---------------------------------------------------------------------------
// Phase 0a: pre-split W_ih into bf16 hi/lo ONCE.
// ---------------------------------------------------------------------------
__global__ __launch_bounds__(256) void presplit_w(
    const float* __restrict__ W, unsigned short* __restrict__ hi,
    unsigned short* __restrict__ lo) {
  const int idx = (blockIdx.x * 256 + threadIdx.x) * 4;
  float4 v = *(const float4*)(W + idx);
  unsigned short h0, l0, h1, l1, h2, l2, h3, l3;
  split_bf16(v.x, h0, l0);
  split_bf16(v.y, h1, l1);
  split_bf16(v.z, h2, l2);
  split_bf16(v.w, h3, l3);
  *(u16x4*)(hi + idx) = u16x4{h0, h1, h2, h3};
  *(u16x4*)(lo + idx) = u16x4{l0, l1, l2, l3};
}

// ---------------------------------------------------------------------------
// Phase 0b: W_hh fp32 -> f16.
// ---------------------------------------------------------------------------
__global__ __launch_bounds__(256) void whh_to_f16(
    const float* __restrict__ W, _Float16* __restrict__ o) {
  const int idx = (blockIdx.x * 256 + threadIdx.x) * 4;
  float4 v = *(const float4*)(W + idx);
  f16x4 r = {(_Float16)v.x, (_Float16)v.y, (_Float16)v.z, (_Float16)v.w};
  *(f16x4*)(o + idx) = r;
}

// ---------------------------------------------------------------------------
// Phase 1 (MFMA): xproj[t,b,j] = sum_f x[t,b,f]*W_ih[j,f] + b_ih[j] + b_hh[j]
// 128x256 tile, 8 waves, bf16-split 3-MFMA, BK=32; W pre-split from ws.
// ---------------------------------------------------------------------------
#define BM 128
#define BK 32
#define LDSP 40  // padded row stride in ushorts

__global__ __launch_bounds__(512) void xproj_mfma(
    const float* __restrict__ x, const unsigned short* __restrict__ Whi_g,
    const unsigned short* __restrict__ Wlo_g, const float* __restrict__ b_ih,
    const float* __restrict__ b_hh, float* __restrict__ xproj) {
  __shared__ alignas(16) unsigned short Xhi[BM][LDSP];
  __shared__ alignas(16) unsigned short Xlo[BM][LDSP];
  __shared__ alignas(16) unsigned short Whi[G4][LDSP];
  __shared__ alignas(16) unsigned short Wlo[G4][LDSP];

  const int tid = threadIdx.x;
  const int lane = tid & 63;
  const int wave = tid >> 6;  // 0..7
  const int wm = wave >> 2;   // 0..1 (M)
  const int wn = wave & 3;    // 0..3 (N)
  const size_t R0 = (size_t)blockIdx.x * BM;

  const int xr = tid >> 2;
  const int xs = (tid & 3) * 8;
  const int wr = tid >> 1;
  const int wsg = (tid & 1) * 16;

  const float* xbase = x + (R0 + xr) * (size_t)F_SZ + xs;
  const unsigned short* whb = Whi_g + (size_t)wr * F_SZ + wsg;
  const unsigned short* wlb = Wlo_g + (size_t)wr * F_SZ + wsg;

  float4 xa = *(const float4*)(xbase + 0);
  float4 xb = *(const float4*)(xbase + 4);
  u16x8 wh0 = *(const u16x8*)(whb + 0);
  u16x8 wh1 = *(const u16x8*)(whb + 8);
  u16x8 wl0 = *(const u16x8*)(wlb + 0);
  u16x8 wl1 = *(const u16x8*)(wlb + 8);

  f32x4 acc[4][4] = {};

  const int ar = lane & 15;
  const int ak = (lane >> 4) * 8;

  for (int kt = 0; kt < F_SZ; kt += BK) {
    {
      float xf[8] = {xa.x, xa.y, xa.z, xa.w, xb.x, xb.y, xb.z, xb.w};
      u16x8 xh, xl;
#pragma unroll
      for (int i = 0; i < 8; ++i) {
        unsigned short h, l;
        split_bf16(xf[i], h, l);
        xh[i] = h;
        xl[i] = l;
      }
      *(u16x8*)&Xhi[xr][xs] = xh;
      *(u16x8*)&Xlo[xr][xs] = xl;
      *(u16x8*)&Whi[wr][wsg] = wh0;
      *(u16x8*)&Whi[wr][wsg + 8] = wh1;
      *(u16x8*)&Wlo[wr][wsg] = wl0;
      *(u16x8*)&Wlo[wr][wsg + 8] = wl1;
    }
    __syncthreads();

    const int ktn = (kt + BK < F_SZ) ? kt + BK : kt;
    xa = *(const float4*)(xbase + ktn + 0);
    xb = *(const float4*)(xbase + ktn + 4);
    wh0 = *(const u16x8*)(whb + ktn + 0);
    wh1 = *(const u16x8*)(whb + ktn + 8);
    wl0 = *(const u16x8*)(wlb + ktn + 0);
    wl1 = *(const u16x8*)(wlb + ktn + 8);

    bf16x8 Ah[4], Al[4], Bh[4], Bl[4];
#pragma unroll
    for (int fm = 0; fm < 4; ++fm) {
      const int row = wm * 64 + fm * 16 + ar;
      Ah[fm] = __builtin_bit_cast(bf16x8, *(const u16x8*)&Xhi[row][ak]);
      Al[fm] = __builtin_bit_cast(bf16x8, *(const u16x8*)&Xlo[row][ak]);
    }
#pragma unroll
    for (int fn = 0; fn < 4; ++fn) {
      const int col = wn * 64 + fn * 16 + ar;
      Bh[fn] = __builtin_bit_cast(bf16x8, *(const u16x8*)&Whi[col][ak]);
      Bl[fn] = __builtin_bit_cast(bf16x8, *(const u16x8*)&Wlo[col][ak]);
    }
#pragma unroll
    for (int fm = 0; fm < 4; ++fm) {
#pragma unroll
      for (int fn = 0; fn < 4; ++fn) {
        acc[fm][fn] = __builtin_amdgcn_mfma_f32_16x16x32_bf16(
            Ah[fm], Bh[fn], acc[fm][fn], 0, 0, 0);
        acc[fm][fn] = __builtin_amdgcn_mfma_f32_16x16x32_bf16(
            Ah[fm], Bl[fn], acc[fm][fn], 0, 0, 0);
        acc[fm][fn] = __builtin_amdgcn_mfma_f32_16x16x32_bf16(
            Al[fm], Bh[fn], acc[fm][fn], 0, 0, 0);
      }
    }
    __syncthreads();
  }

  const int cr = (lane >> 4) * 4;
  const int cc = lane & 15;
#pragma unroll
  for (int fn = 0; fn < 4; ++fn) {
    const int gj = wn * 64 + fn * 16 + cc;
    const float bias = b_ih[gj] + b_hh[gj];
#pragma unroll
    for (int fm = 0; fm < 4; ++fm) {
      const size_t gr = R0 + wm * 64 + fm * 16 + cr;
#pragma unroll
      for (int r = 0; r < 4; ++r) {
        xproj[(gr + r) * G4 + gj] = acc[fm][fn][r] + bias;
      }
    }
  }
}

// ---------------------------------------------------------------------------
// Phase 2: LSTM scan, ONE WAVE PER BATCH, ZERO BARRIERS, f16 weights,
// counted-vmcnt x-pipeline, UNROLL x4 with 4 NAMED REGISTER SETS (no
// rotation movs — R12's movs read in-flight load destinations: stale data).
//  - prologue issues t=0..3 (16 outstanding dwords);
//  - slot s: s_waitcnt vmcnt(12) bound "+v" to set s (oldest 4 retire,
//    12 stay in flight) -> consume -> re-issue set s for t+4;
//  - WAR on re-issue is safe: in-order issue + SSA live ranges, no movs;
//  - prefetch depth 4 steps (~2200cyc) >> 900cyc HBM latency;
//  - T=1024 % 4 == 0: no tail; issue addr clamps at t=1023 (never consumed).
// W pinned in VGPR (asm volatile + waves_per_eu(1,1), R10-proven).
// ---------------------------------------------------------------------------
__global__ __attribute__((amdgpu_flat_work_group_size(64, 64)))
__attribute__((amdgpu_waves_per_eu(1, 1))) void lstm_scan_f16(
    const float* __restrict__ xproj, const _Float16* __restrict__ Whh16,
    float* __restrict__ hT) {
  const int b = blockIdx.x;   // 0..31
  const int u = threadIdx.x;  // 0..63

  __shared__ alignas(16) _Float16 hbuf[2][H_SZ];

  // --- pin 4 gate rows (f16): 32 quads = 128 VGPRs ---
  const _Float16* wp = Whh16 + (size_t)u * H_SZ;  // gate g row at +g*4096
#define PINW(i)                                                               \
  f32x4 w0_##i, w1_##i, w2_##i, w3_##i;                                       \
  {                                                                           \
    const _Float16* a0 = wp + 0 * 4096 + 8 * (i);                             \
    const _Float16* a1 = wp + 1 * 4096 + 8 * (i);                             \
    const _Float16* a2 = wp + 2 * 4096 + 8 * (i);                             \
    const _Float16* a3 = wp + 3 * 4096 + 8 * (i);                             \
    asm volatile("global_load_dwordx4 %0, %1, off" : "=v"(w0_##i) : "v"(a0)); \
    asm volatile("global_load_dwordx4 %0, %1, off" : "=v"(w1_##i) : "v"(a1)); \
    asm volatile("global_load_dwordx4 %0, %1, off" : "=v"(w2_##i) : "v"(a2)); \
    asm volatile("global_load_dwordx4 %0, %1, off" : "=v"(w3_##i) : "v"(a3)); \
  }
  REP8(PINW)
#undef PINW
  asm volatile("s_waitcnt vmcnt(0)" ::: "memory");

  hbuf[0][u] = (_Float16)0.f;
  float c = 0.f, hval = 0.f;
  int p = 0;

  const float* a_next = xproj + (size_t)b * G4 + u;
  const size_t step_off = (size_t)B_SZ * G4;  // floats per t

  // 4 named register sets; loads via one vaddr + offset:0/256/512/768
  float xi0, xf0, xg0, xo0, xi1, xf1, xg1, xo1;
  float xi2, xf2, xg2, xo2, xi3, xf3, xg3, xo3;

#define XLOAD(S, a)                                                    \
  asm volatile("global_load_dword %0, %4, off\n\t"                     \
               "global_load_dword %1, %4, off offset:256\n\t"          \
               "global_load_dword %2, %4, off offset:512\n\t"          \
               "global_load_dword %3, %4, off offset:768"              \
               : "=&v"(xi##S), "=&v"(xf##S), "=&v"(xg##S), "=&v"(xo##S) \
               : "v"(a));

  // prologue: t = 0..3 in flight (16 outstanding)
  XLOAD(0, a_next) a_next += step_off;
  XLOAD(1, a_next) a_next += step_off;
  XLOAD(2, a_next) a_next += step_off;
  XLOAD(3, a_next) a_next += step_off;  // points at t=4

  for (int it = 0; it < T_STEPS / 4; ++it) {
    const int tb = it * 4;

#define SLOT(S)                                                               \
    {                                                                         \
      /* oldest 4 loads (set S) retire; 12 stay in flight */                  \
      asm volatile("s_waitcnt vmcnt(12)"                                      \
                   : "+v"(xi##S), "+v"(xf##S), "+v"(xg##S), "+v"(xo##S));     \
      const f32x4 hq_0 = *(const f32x4*)&hbuf[p][0];                          \
      const f32x4 hq_1 = *(const f32x4*)&hbuf[p][8];                          \
      const f32x4 hq_2 = *(const f32x4*)&hbuf[p][16];                         \
      const f32x4 hq_3 = *(const f32x4*)&hbuf[p][24];                         \
      const f32x4 hq_4 = *(const f32x4*)&hbuf[p][32];                         \
      const f32x4 hq_5 = *(const f32x4*)&hbuf[p][40];                         \
      const f32x4 hq_6 = *(const f32x4*)&hbuf[p][48];                         \
      const f32x4 hq_7 = *(const f32x4*)&hbuf[p][56];                         \
      float aiA = xi##S, aiB = 0.f, afA = xf##S, afB = 0.f;                   \
      float agA = xg##S, agB = 0.f, aoA = xo##S, aoB = 0.f;                   \
      DOTQ(aiA, 0, w0) DOTQ(aiA, 1, w0) DOTQ(aiA, 2, w0) DOTQ(aiA, 3, w0)     \
      DOTQ(aiB, 4, w0) DOTQ(aiB, 5, w0) DOTQ(aiB, 6, w0) DOTQ(aiB, 7, w0)     \
      DOTQ(afA, 0, w1) DOTQ(afA, 1, w1) DOTQ(afA, 2, w1) DOTQ(afA, 3, w1)     \
      DOTQ(afB, 4, w1) DOTQ(afB, 5, w1) DOTQ(afB, 6, w1) DOTQ(afB, 7, w1)     \
      DOTQ(agA, 0, w2) DOTQ(agA, 1, w2) DOTQ(agA, 2, w2) DOTQ(agA, 3, w2)     \
      DOTQ(agB, 4, w2) DOTQ(agB, 5, w2) DOTQ(agB, 6, w2) DOTQ(agB, 7, w2)     \
      DOTQ(aoA, 0, w3) DOTQ(aoA, 1, w3) DOTQ(aoA, 2, w3) DOTQ(aoA, 3, w3)     \
      DOTQ(aoB, 4, w3) DOTQ(aoB, 5, w3) DOTQ(aoB, 6, w3) DOTQ(aoB, 7, w3)     \
      const float pi = aiA + aiB;                                             \
      const float pf = afA + afB;                                             \
      const float pg = agA + agB;                                             \
      const float po = aoA + aoB;                                             \
      c = sigm_f(pf) * c + sigm_f(pi) * tanh_f(pg);                           \
      hval = sigm_f(po) * tanh_f(c);                                          \
      hbuf[p ^ 1][u] = (_Float16)hval;                                        \
      p ^= 1;                                                                 \
      /* re-issue set S for t+4 (clamped addr near tail; never consumed) */   \
      XLOAD(S, a_next)                                                        \
      if (tb + (S) + 4 < T_STEPS - 1) a_next += step_off;                     \
    }

#define DOTQ(acc, i, wg)                         \
    acc = dot2(hq_##i[0], wg##_##i[0], acc);     \
    acc = dot2(hq_##i[1], wg##_##i[1], acc);     \
    acc = dot2(hq_##i[2], wg##_##i[2], acc);     \
    acc = dot2(hq_##i[3], wg##_##i[3], acc);

    SLOT(0)
    SLOT(1)
    SLOT(2)
    SLOT(3)

#undef DOTQ
#undef SLOT
  }
#undef XLOAD

  hT[b * H_SZ + u] = hval;
}

// ---------------------------------------------------------------------------
// Phase 3: out[b][c] = sum_k hT[b][k] * W_lin[c][k] + b_lin[c]
// ---------------------------------------------------------------------------
__global__ __launch_bounds__(128) void final_linear_kernel(
    const float* __restrict__ hT, const float* __restrict__ W_lin,
    const float* __restrict__ b_lin, float* __restrict__ out) {
  const int b = blockIdx.x;
  const int cc = threadIdx.x;

  __shared__ float h_l[H_SZ];
  if (threadIdx.x < H_SZ) h_l[threadIdx.x] = hT[b * H_SZ + threadIdx.x];
  __syncthreads();

  if (cc < C_SZ) {
    float acc = b_lin[cc];
    const float* wr = W_lin + (size_t)cc * H_SZ;
#pragma unroll
    for (int k = 0; k < H_SZ; ++k) acc += h_l[k] * wr[k];
    out[b * C_SZ + cc] = acc;
  }
}

// ---------------------------------------------------------------------------
extern "C" void kernel_launch(void* const* d_in, const int* in_sizes, int n_in,
                              void* d_out, int out_size, void* d_ws,
                              size_t ws_size, hipStream_t stream) {
  const float* x = (const float*)d_in[0];      // [T,B,F]
  const float* W_ih = (const float*)d_in[1];   // [4H,F]
  const float* W_hh = (const float*)d_in[2];   // [4H,H]
  const float* b_ih = (const float*)d_in[3];   // [4H]
  const float* b_hh = (const float*)d_in[4];   // [4H]
  const float* W_lin = (const float*)d_in[5];  // [C,H]
  const float* b_lin = (const float*)d_in[6];  // [C]
  float* out = (float*)d_out;                  // [B,C]

  // ws layout: xproj 32MB | hT 8KB | Whi 1MB | Wlo 1MB | Whh_f16 32KB
  const size_t XP_BYTES = (size_t)T_STEPS * B_SZ * G4 * sizeof(float);
  float* xproj = (float*)d_ws;
  float* hT = (float*)((char*)d_ws + XP_BYTES);
  unsigned short* Whi_g = (unsigned short*)((char*)d_ws + XP_BYTES + 8192);
  unsigned short* Wlo_g = Whi_g + (size_t)G4 * F_SZ;
  _Float16* Whh16 = (_Float16*)(Wlo_g + (size_t)G4 * F_SZ);

  presplit_w<<<512, 256, 0, stream>>>(W_ih, Whi_g, Wlo_g);
  whh_to_f16<<<16, 256, 0, stream>>>(W_hh, Whh16);
  xproj_mfma<<<(T_STEPS * B_SZ) / BM, 512, 0, stream>>>(x, Whi_g, Wlo_g, b_ih,
                                                        b_hh, xproj);
  lstm_scan_f16<<<B_SZ, 64, 0, stream>>>(xproj, Whh16, hT);
  final_linear_kernel<<<B_SZ, 128, 0, stream>>>(hT, W_lin, b_lin, out);
}

// Round 14
// 536.913 us; speedup vs baseline: 1.1647x; 1.0301x over previous
//
#include <hip/hip_runtime.h>
#include <hip/hip_bf16.h>
#include <math.h>

// Sizes (fixed by the problem)
#define T_STEPS 1024
#define B_SZ 32
#define F_SZ 2048
#define H_SZ 64
#define G4 256      // 4*H
#define C_SZ 101

typedef __bf16 bf16x8 __attribute__((ext_vector_type(8)));
typedef unsigned short u16x8 __attribute__((ext_vector_type(8)));
typedef unsigned short u16x4 __attribute__((ext_vector_type(4)));
typedef float f32x4 __attribute__((ext_vector_type(4)));
typedef _Float16 f16x4 __attribute__((ext_vector_type(4)));
typedef _Float16 f16x8 __attribute__((ext_vector_type(8)));

// Round-to-nearest-even fp32 -> bf16 split: f ~= hi + lo (each bf16).
__device__ __forceinline__ void split_bf16(float f, unsigned short& h,
                                           unsigned short& l) {
  unsigned u = __builtin_bit_cast(unsigned, f);
  unsigned rh = (u + 0x7FFFu + ((u >> 16) & 1u)) >> 16;
  h = (unsigned short)rh;
  float d = f - __builtin_bit_cast(float, rh << 16);
  unsigned ud = __builtin_bit_cast(unsigned, d);
  l = (unsigned short)((ud + 0x7FFFu + ((ud >> 16) & 1u)) >> 16);
}

__device__ __forceinline__ float sigm_f(float x) {
  return __builtin_amdgcn_rcpf(1.f + __expf(-x));
}
__device__ __forceinline__ float tanh_f(float x) {
  return 2.f * __builtin_amdgcn_rcpf(1.f + __expf(-2.f * x)) - 1.f;
}

// static 4-way select on precomputed lane bits (no runtime indexing -> no scratch)
__device__ __forceinline__ float sel4(float a0, float a1, float a2, float a3,
                                      bool k1, bool k2) {
  const float t0 = k1 ? a1 : a0;
  const float t1 = k1 ? a3 : a2;
  return k2 ? t1 : t0;
}

#define REP8(M) M(0) M(1) M(2) M(3) M(4) M(5) M(6) M(7)
#define REP16(M) M(0) M(1) M(2) M(3) M(4) M(5) M(6) M(7) \
                 M(8) M(9) M(10) M(11) M(12) M(13) M(14) M(15)

// ---------------------------------------------------------------------------
// Phase 0a: pre-split W_ih into bf16 hi/lo ONCE.
// ---------------------------------------------------------------------------
__global__ __launch_bounds__(256) void presplit_w(
    const float* __restrict__ W, unsigned short* __restrict__ hi,
    unsigned short* __restrict__ lo) {
  const int idx = (blockIdx.x * 256 + threadIdx.x) * 4;
  float4 v = *(const float4*)(W + idx);
  unsigned short h0, l0, h1, l1, h2, l2, h3, l3;
  split_bf16(v.x, h0, l0);
  split_bf16(v.y, h1, l1);
  split_bf16(v.z, h2, l2);
  split_bf16(v.w, h3, l3);
  *(u16x4*)(hi + idx) = u16x4{h0, h1, h2, h3};
  *(u16x4*)(lo + idx) = u16x4{l0, l1, l2, l3};
}

// ---------------------------------------------------------------------------
// Phase 0b: W_hh fp32 -> f16.
// ---------------------------------------------------------------------------
__global__ __launch_bounds__(256) void whh_to_f16(
    const float* __restrict__ W, _Float16* __restrict__ o) {
  const int idx = (blockIdx.x * 256 + threadIdx.x) * 4;
  float4 v = *(const float4*)(W + idx);
  f16x4 r = {(_Float16)v.x, (_Float16)v.y, (_Float16)v.z, (_Float16)v.w};
  *(f16x4*)(o + idx) = r;
}

// ---------------------------------------------------------------------------
// Phase 1 (MFMA): xproj[t,b,j] = sum_f x[t,b,f]*W_ih[j,f] + b_ih[j] + b_hh[j]
// 128x256 tile, 8 waves, bf16-split 3-MFMA, BK=32; W pre-split from ws.
// ---------------------------------------------------------------------------
#define BM 128
#define BK 32
#define LDSP 40  // padded row stride in ushorts

__global__ __launch_bounds__(512) void xproj_mfma(
    const float* __restrict__ x, const unsigned short* __restrict__ Whi_g,
    const unsigned short* __restrict__ Wlo_g, const float* __restrict__ b_ih,
    const float* __restrict__ b_hh, float* __restrict__ xproj) {
  __shared__ alignas(16) unsigned short Xhi[BM][LDSP];
  __shared__ alignas(16) unsigned short Xlo[BM][LDSP];
  __shared__ alignas(16) unsigned short Whi[G4][LDSP];
  __shared__ alignas(16) unsigned short Wlo[G4][LDSP];

  const int tid = threadIdx.x;
  const int lane = tid & 63;
  const int wave = tid >> 6;  // 0..7
  const int wm = wave >> 2;   // 0..1 (M)
  const int wn = wave & 3;    // 0..3 (N)
  const size_t R0 = (size_t)blockIdx.x * BM;

  const int xr = tid >> 2;
  const int xs = (tid & 3) * 8;
  const int wr = tid >> 1;
  const int wsg = (tid & 1) * 16;

  const float* xbase = x + (R0 + xr) * (size_t)F_SZ + xs;
  const unsigned short* whb = Whi_g + (size_t)wr * F_SZ + wsg;
  const unsigned short* wlb = Wlo_g + (size_t)wr * F_SZ + wsg;

  float4 xa = *(const float4*)(xbase + 0);
  float4 xb = *(const float4*)(xbase + 4);
  u16x8 wh0 = *(const u16x8*)(whb + 0);
  u16x8 wh1 = *(const u16x8*)(whb + 8);
  u16x8 wl0 = *(const u16x8*)(wlb + 0);
  u16x8 wl1 = *(const u16x8*)(wlb + 8);

  f32x4 acc[4][4] = {};

  const int ar = lane & 15;
  const int ak = (lane >> 4) * 8;

  for (int kt = 0; kt < F_SZ; kt += BK) {
    {
      float xf[8] = {xa.x, xa.y, xa.z, xa.w, xb.x, xb.y, xb.z, xb.w};
      u16x8 xh, xl;
#pragma unroll
      for (int i = 0; i < 8; ++i) {
        unsigned short h, l;
        split_bf16(xf[i], h, l);
        xh[i] = h;
        xl[i] = l;
      }
      *(u16x8*)&Xhi[xr][xs] = xh;
      *(u16x8*)&Xlo[xr][xs] = xl;
      *(u16x8*)&Whi[wr][wsg] = wh0;
      *(u16x8*)&Whi[wr][wsg + 8] = wh1;
      *(u16x8*)&Wlo[wr][wsg] = wl0;
      *(u16x8*)&Wlo[wr][wsg + 8] = wl1;
    }
    __syncthreads();

    const int ktn = (kt + BK < F_SZ) ? kt + BK : kt;
    xa = *(const float4*)(xbase + ktn + 0);
    xb = *(const float4*)(xbase + ktn + 4);
    wh0 = *(const u16x8*)(whb + ktn + 0);
    wh1 = *(const u16x8*)(whb + ktn + 8);
    wl0 = *(const u16x8*)(wlb + ktn + 0);
    wl1 = *(const u16x8*)(wlb + ktn + 8);

    bf16x8 Ah[4], Al[4], Bh[4], Bl[4];
#pragma unroll
    for (int fm = 0; fm < 4; ++fm) {
      const int row = wm * 64 + fm * 16 + ar;
      Ah[fm] = __builtin_bit_cast(bf16x8, *(const u16x8*)&Xhi[row][ak]);
      Al[fm] = __builtin_bit_cast(bf16x8, *(const u16x8*)&Xlo[row][ak]);
    }
#pragma unroll
    for (int fn = 0; fn < 4; ++fn) {
      const int col = wn * 64 + fn * 16 + ar;
      Bh[fn] = __builtin_bit_cast(bf16x8, *(const u16x8*)&Whi[col][ak]);
      Bl[fn] = __builtin_bit_cast(bf16x8, *(const u16x8*)&Wlo[col][ak]);
    }
#pragma unroll
    for (int fm = 0; fm < 4; ++fm) {
#pragma unroll
      for (int fn = 0; fn < 4; ++fn) {
        acc[fm][fn] = __builtin_amdgcn_mfma_f32_16x16x32_bf16(
            Ah[fm], Bh[fn], acc[fm][fn], 0, 0, 0);
        acc[fm][fn] = __builtin_amdgcn_mfma_f32_16x16x32_bf16(
            Ah[fm], Bl[fn], acc[fm][fn], 0, 0, 0);
        acc[fm][fn] = __builtin_amdgcn_mfma_f32_16x16x32_bf16(
            Al[fm], Bh[fn], acc[fm][fn], 0, 0, 0);
      }
    }
    __syncthreads();
  }

  const int cr = (lane >> 4) * 4;
  const int cc = lane & 15;
#pragma unroll
  for (int fn = 0; fn < 4; ++fn) {
    const int gj = wn * 64 + fn * 16 + cc;
    const float bias = b_ih[gj] + b_hh[gj];
#pragma unroll
    for (int fm = 0; fm < 4; ++fm) {
      const size_t gr = R0 + wm * 64 + fm * 16 + cr;
#pragma unroll
      for (int r = 0; r < 4; ++r) {
        xproj[(gr + r) * G4 + gj] = acc[fm][fn][r] + bias;
      }
    }
  }
}

// ---------------------------------------------------------------------------
// Phase 2: LSTM scan via MFMA BROADCAST TRICK. One wave per batch, zero
// barriers, f16 weights, R13's counted-vmcnt x-pipeline (proven).
// Recurrent matvec h(1x64)·W^T(64x256) done as 16 N-tiles x 2 K-slices of
// mfma_f32_16x16x32_f16 where EVERY lane loads the same h fragment for its
// k-group -> A[m][k]=h[k] for all m -> all 16 C rows identical -> lane l
// holds the result for col (l&15) of every tile. Gate g of unit u=l lives
// in tile g*4+(l>>4) at col l&15 -> in-lane after a static 4-way cndmask
// select. Issue: 32 mfma (~160cyc) replaces 128 dot2 (256cyc); LDS reads
// drop 8->2 per step. Accumulators land in AGPRs (unified file) so the
// 256 v-reg cap (R9 abort) is not in play: v-budget = 128 W + 16 x + misc.
// W tile/kslice quad: Whh16[(n*16 + (l&15))*64 + s*32 + (l>>4)*8], pinned
// via asm volatile + waves_per_eu(1,1) (R10/R13-proven mechanism).
// ---------------------------------------------------------------------------
__global__ __attribute__((amdgpu_flat_work_group_size(64, 64)))
__attribute__((amdgpu_waves_per_eu(1, 1))) void lstm_scan_mfma(
    const float* __restrict__ xproj, const _Float16* __restrict__ Whh16,
    float* __restrict__ hT) {
  const int b = blockIdx.x;   // 0..31
  const int l = threadIdx.x;  // lane = unit u
  const int kg8 = (l >> 4) * 8;
  const bool k1 = ((l >> 4) & 1) != 0;
  const bool k2 = ((l >> 4) & 2) != 0;

  __shared__ alignas(16) _Float16 hbuf[2][H_SZ];

  // --- pin B-fragments: 16 tiles x 2 kslices = 32 quads = 128 VGPRs ---
  const _Float16* wb = Whh16 + (size_t)(l & 15) * H_SZ + kg8;
#define PINB(n)                                                               \
  f32x4 wB0_##n, wB1_##n;                                                     \
  {                                                                           \
    const _Float16* a0_##n = wb + (n) * (16 * H_SZ);                          \
    const _Float16* a1_##n = wb + (n) * (16 * H_SZ) + 32;                     \
    asm volatile("global_load_dwordx4 %0, %1, off" : "=v"(wB0_##n) : "v"(a0_##n)); \
    asm volatile("global_load_dwordx4 %0, %1, off" : "=v"(wB1_##n) : "v"(a1_##n)); \
  }
  REP16(PINB)
#undef PINB
  asm volatile("s_waitcnt vmcnt(0)" ::: "memory");

  hbuf[0][l] = (_Float16)0.f;
  float c = 0.f, hval = 0.f;
  int p = 0;

  const float* a_next = xproj + (size_t)b * G4 + l;
  const size_t step_off = (size_t)B_SZ * G4;  // floats per t

  float xi0, xf0, xg0, xo0, xi1, xf1, xg1, xo1;
  float xi2, xf2, xg2, xo2, xi3, xf3, xg3, xo3;

#define XLOAD(S, a)                                                     \
  asm volatile("global_load_dword %0, %4, off\n\t"                      \
               "global_load_dword %1, %4, off offset:256\n\t"           \
               "global_load_dword %2, %4, off offset:512\n\t"           \
               "global_load_dword %3, %4, off offset:768"               \
               : "=&v"(xi##S), "=&v"(xf##S), "=&v"(xg##S), "=&v"(xo##S) \
               : "v"(a));

  // prologue: t = 0..3 in flight (16 outstanding)
  XLOAD(0, a_next) a_next += step_off;
  XLOAD(1, a_next) a_next += step_off;
  XLOAD(2, a_next) a_next += step_off;
  XLOAD(3, a_next) a_next += step_off;  // points at t=4

  for (int it = 0; it < T_STEPS / 4; ++it) {
    const int tb = it * 4;

#define TILE(n)                                                               \
    f32x4 acc_##n = {0.f, 0.f, 0.f, 0.f};                                     \
    acc_##n = __builtin_amdgcn_mfma_f32_16x16x32_f16(                         \
        hA0, __builtin_bit_cast(f16x8, wB0_##n), acc_##n, 0, 0, 0);           \
    acc_##n = __builtin_amdgcn_mfma_f32_16x16x32_f16(                         \
        hA1, __builtin_bit_cast(f16x8, wB1_##n), acc_##n, 0, 0, 0);

#define SLOT(S)                                                               \
    {                                                                         \
      /* oldest 4 x-loads retire; 12 stay in flight */                        \
      asm volatile("s_waitcnt vmcnt(12)"                                      \
                   : "+v"(xi##S), "+v"(xf##S), "+v"(xg##S), "+v"(xo##S));     \
      /* A fragments: same h quad for every lane in a k-group (broadcast) */  \
      const f16x8 hA0 = *(const f16x8*)&hbuf[p][kg8];                         \
      const f16x8 hA1 = *(const f16x8*)&hbuf[p][32 + kg8];                    \
      REP16(TILE)                                                             \
      /* gate g of unit l: tile g*4+(l>>4), col l&15; rows identical */       \
      const float di = sel4(acc_0[0], acc_1[0], acc_2[0], acc_3[0], k1, k2);  \
      const float df = sel4(acc_4[0], acc_5[0], acc_6[0], acc_7[0], k1, k2);  \
      const float dg = sel4(acc_8[0], acc_9[0], acc_10[0], acc_11[0], k1, k2);\
      const float dq = sel4(acc_12[0], acc_13[0], acc_14[0], acc_15[0], k1, k2);\
      const float pi = xi##S + di;                                            \
      const float pf = xf##S + df;                                            \
      const float pg = xg##S + dg;                                            \
      const float po = xo##S + dq;                                            \
      c = sigm_f(pf) * c + sigm_f(pi) * tanh_f(pg);                           \
      hval = sigm_f(po) * tanh_f(c);                                          \
      hbuf[p ^ 1][l] = (_Float16)hval;                                        \
      p ^= 1;                                                                 \
      /* re-issue set S for t+4 (clamped addr near tail; never consumed) */   \
      XLOAD(S, a_next)                                                        \
      if (tb + (S) + 4 < T_STEPS - 1) a_next += step_off;                     \
    }

    SLOT(0)
    SLOT(1)
    SLOT(2)
    SLOT(3)

#undef SLOT
#undef TILE
  }
#undef XLOAD

  hT[b * H_SZ + l] = hval;
}

// ---------------------------------------------------------------------------
// Phase 3: out[b][c] = sum_k hT[b][k] * W_lin[c][k] + b_lin[c]
// ---------------------------------------------------------------------------
__global__ __launch_bounds__(128) void final_linear_kernel(
    const float* __restrict__ hT, const float* __restrict__ W_lin,
    const float* __restrict__ b_lin, float* __restrict__ out) {
  const int b = blockIdx.x;
  const int cc = threadIdx.x;

  __shared__ float h_l[H_SZ];
  if (threadIdx.x < H_SZ) h_l[threadIdx.x] = hT[b * H_SZ + threadIdx.x];
  __syncthreads();

  if (cc < C_SZ) {
    float acc = b_lin[cc];
    const float* wr = W_lin + (size_t)cc * H_SZ;
#pragma unroll
    for (int k = 0; k < H_SZ; ++k) acc += h_l[k] * wr[k];
    out[b * C_SZ + cc] = acc;
  }
}

// ---------------------------------------------------------------------------
extern "C" void kernel_launch(void* const* d_in, const int* in_sizes, int n_in,
                              void* d_out, int out_size, void* d_ws,
                              size_t ws_size, hipStream_t stream) {
  const float* x = (const float*)d_in[0];      // [T,B,F]
  const float* W_ih = (const float*)d_in[1];   // [4H,F]
  const float* W_hh = (const float*)d_in[2];   // [4H,H]
  const float* b_ih = (const float*)d_in[3];   // [4H]
  const float* b_hh = (const float*)d_in[4];   // [4H]
  const float* W_lin = (const float*)d_in[5];  // [C,H]
  const float* b_lin = (const float*)d_in[6];  // [C]
  float* out = (float*)d_out;                  // [B,C]

  // ws layout: xproj 32MB | hT 8KB | Whi 1MB | Wlo 1MB | Whh_f16 32KB
  const size_t XP_BYTES = (size_t)T_STEPS * B_SZ * G4 * sizeof(float);
  float* xproj = (float*)d_ws;
  float* hT = (float*)((char*)d_ws + XP_BYTES);
  unsigned short* Whi_g = (unsigned short*)((char*)d_ws + XP_BYTES + 8192);
  unsigned short* Wlo_g = Whi_g + (size_t)G4 * F_SZ;
  _Float16* Whh16 = (_Float16*)(Wlo_g + (size_t)G4 * F_SZ);

  presplit_w<<<512, 256, 0, stream>>>(W_ih, Whi_g, Wlo_g);
  whh_to_f16<<<16, 256, 0, stream>>>(W_hh, Whh16);
  xproj_mfma<<<(T_STEPS * B_SZ) / BM, 512, 0, stream>>>(x, Whi_g, Wlo_g, b_ih,
                                                        b_hh, xproj);
  lstm_scan_mfma<<<B_SZ, 64, 0, stream>>>(xproj, Whh16, hT);
  final_linear_kernel<<<B_SZ, 128, 0, stream>>>(hT, W_lin, b_lin, out);
}

// Round 15
// 535.764 us; speedup vs baseline: 1.1672x; 1.0021x over previous
//
#include <hip/hip_runtime.h>
#include <hip/hip_bf16.h>
#include <math.h>

// Sizes (fixed by the problem)
#define T_STEPS 1024
#define B_SZ 32
#define F_SZ 2048
#define H_SZ 64
#define G4 256      // 4*H
#define C_SZ 101

typedef __bf16 bf16x8 __attribute__((ext_vector_type(8)));
typedef unsigned short u16x8 __attribute__((ext_vector_type(8)));
typedef unsigned short u16x4 __attribute__((ext_vector_type(4)));
typedef float f32x4 __attribute__((ext_vector_type(4)));
typedef _Float16 f16x4 __attribute__((ext_vector_type(4)));
typedef _Float16 f16x8 __attribute__((ext_vector_type(8)));

// Round-to-nearest-even fp32 -> bf16 split: f ~= hi + lo (each bf16).
__device__ __forceinline__ void split_bf16(float f, unsigned short& h,
                                           unsigned short& l) {
  unsigned u = __builtin_bit_cast(unsigned, f);
  unsigned rh = (u + 0x7FFFu + ((u >> 16) & 1u)) >> 16;
  h = (unsigned short)rh;
  float d = f - __builtin_bit_cast(float, rh << 16);
  unsigned ud = __builtin_bit_cast(unsigned, d);
  l = (unsigned short)((ud + 0x7FFFu + ((ud >> 16) & 1u)) >> 16);
}

__device__ __forceinline__ float sigm_f(float x) {
  return __builtin_amdgcn_rcpf(1.f + __expf(-x));
}
__device__ __forceinline__ float tanh_f(float x) {
  return 2.f * __builtin_amdgcn_rcpf(1.f + __expf(-2.f * x)) - 1.f;
}

// static 4-way select on precomputed lane bits (no runtime indexing -> no scratch)
__device__ __forceinline__ float sel4(float a0, float a1, float a2, float a3,
                                      bool k1, bool k2) {
  const float t0 = k1 ? a1 : a0;
  const float t1 = k1 ? a3 : a2;
  return k2 ? t1 : t0;
}

#define REP8(M) M(0) M(1) M(2) M(3) M(4) M(5) M(6) M(7)
#define REP16(M) M(0) M(1) M(2) M(3) M(4) M(5) M(6) M(7) \
                 M(8) M(9) M(10) M(11) M(12) M(13) M(14) M(15)

// ---------------------------------------------------------------------------
// Phase 0a: pre-split W_ih into bf16 hi/lo ONCE.
// ---------------------------------------------------------------------------
__global__ __launch_bounds__(256) void presplit_w(
    const float* __restrict__ W, unsigned short* __restrict__ hi,
    unsigned short* __restrict__ lo) {
  const int idx = (blockIdx.x * 256 + threadIdx.x) * 4;
  float4 v = *(const float4*)(W + idx);
  unsigned short h0, l0, h1, l1, h2, l2, h3, l3;
  split_bf16(v.x, h0, l0);
  split_bf16(v.y, h1, l1);
  split_bf16(v.z, h2, l2);
  split_bf16(v.w, h3, l3);
  *(u16x4*)(hi + idx) = u16x4{h0, h1, h2, h3};
  *(u16x4*)(lo + idx) = u16x4{l0, l1, l2, l3};
}

// ---------------------------------------------------------------------------
// Phase 0b: W_hh fp32 -> f16.
// ---------------------------------------------------------------------------
__global__ __launch_bounds__(256) void whh_to_f16(
    const float* __restrict__ W, _Float16* __restrict__ o) {
  const int idx = (blockIdx.x * 256 + threadIdx.x) * 4;
  float4 v = *(const float4*)(W + idx);
  f16x4 r = {(_Float16)v.x, (_Float16)v.y, (_Float16)v.z, (_Float16)v.w};
  *(f16x4*)(o + idx) = r;
}

// ---------------------------------------------------------------------------
// Phase 1 (MFMA): xproj[t,b,j] = sum_f x[t,b,f]*W_ih[j,f] + b_ih[j] + b_hh[j]
// 128x256 tile, 8 waves, bf16-split 3-MFMA, BK=32; W pre-split from ws.
// ---------------------------------------------------------------------------
#define BM 128
#define BK 32
#define LDSP 40  // padded row stride in ushorts

__global__ __launch_bounds__(512) void xproj_mfma(
    const float* __restrict__ x, const unsigned short* __restrict__ Whi_g,
    const unsigned short* __restrict__ Wlo_g, const float* __restrict__ b_ih,
    const float* __restrict__ b_hh, float* __restrict__ xproj) {
  __shared__ alignas(16) unsigned short Xhi[BM][LDSP];
  __shared__ alignas(16) unsigned short Xlo[BM][LDSP];
  __shared__ alignas(16) unsigned short Whi[G4][LDSP];
  __shared__ alignas(16) unsigned short Wlo[G4][LDSP];

  const int tid = threadIdx.x;
  const int lane = tid & 63;
  const int wave = tid >> 6;  // 0..7
  const int wm = wave >> 2;   // 0..1 (M)
  const int wn = wave & 3;    // 0..3 (N)
  const size_t R0 = (size_t)blockIdx.x * BM;

  const int xr = tid >> 2;
  const int xs = (tid & 3) * 8;
  const int wr = tid >> 1;
  const int wsg = (tid & 1) * 16;

  const float* xbase = x + (R0 + xr) * (size_t)F_SZ + xs;
  const unsigned short* whb = Whi_g + (size_t)wr * F_SZ + wsg;
  const unsigned short* wlb = Wlo_g + (size_t)wr * F_SZ + wsg;

  float4 xa = *(const float4*)(xbase + 0);
  float4 xb = *(const float4*)(xbase + 4);
  u16x8 wh0 = *(const u16x8*)(whb + 0);
  u16x8 wh1 = *(const u16x8*)(whb + 8);
  u16x8 wl0 = *(const u16x8*)(wlb + 0);
  u16x8 wl1 = *(const u16x8*)(wlb + 8);

  f32x4 acc[4][4] = {};

  const int ar = lane & 15;
  const int ak = (lane >> 4) * 8;

  for (int kt = 0; kt < F_SZ; kt += BK) {
    {
      float xf[8] = {xa.x, xa.y, xa.z, xa.w, xb.x, xb.y, xb.z, xb.w};
      u16x8 xh, xl;
#pragma unroll
      for (int i = 0; i < 8; ++i) {
        unsigned short h, l;
        split_bf16(xf[i], h, l);
        xh[i] = h;
        xl[i] = l;
      }
      *(u16x8*)&Xhi[xr][xs] = xh;
      *(u16x8*)&Xlo[xr][xs] = xl;
      *(u16x8*)&Whi[wr][wsg] = wh0;
      *(u16x8*)&Whi[wr][wsg + 8] = wh1;
      *(u16x8*)&Wlo[wr][wsg] = wl0;
      *(u16x8*)&Wlo[wr][wsg + 8] = wl1;
    }
    __syncthreads();

    const int ktn = (kt + BK < F_SZ) ? kt + BK : kt;
    xa = *(const float4*)(xbase + ktn + 0);
    xb = *(const float4*)(xbase + ktn + 4);
    wh0 = *(const u16x8*)(whb + ktn + 0);
    wh1 = *(const u16x8*)(whb + ktn + 8);
    wl0 = *(const u16x8*)(wlb + ktn + 0);
    wl1 = *(const u16x8*)(wlb + ktn + 8);

    bf16x8 Ah[4], Al[4], Bh[4], Bl[4];
#pragma unroll
    for (int fm = 0; fm < 4; ++fm) {
      const int row = wm * 64 + fm * 16 + ar;
      Ah[fm] = __builtin_bit_cast(bf16x8, *(const u16x8*)&Xhi[row][ak]);
      Al[fm] = __builtin_bit_cast(bf16x8, *(const u16x8*)&Xlo[row][ak]);
    }
#pragma unroll
    for (int fn = 0; fn < 4; ++fn) {
      const int col = wn * 64 + fn * 16 + ar;
      Bh[fn] = __builtin_bit_cast(bf16x8, *(const u16x8*)&Whi[col][ak]);
      Bl[fn] = __builtin_bit_cast(bf16x8, *(const u16x8*)&Wlo[col][ak]);
    }
#pragma unroll
    for (int fm = 0; fm < 4; ++fm) {
#pragma unroll
      for (int fn = 0; fn < 4; ++fn) {
        acc[fm][fn] = __builtin_amdgcn_mfma_f32_16x16x32_bf16(
            Ah[fm], Bh[fn], acc[fm][fn], 0, 0, 0);
        acc[fm][fn] = __builtin_amdgcn_mfma_f32_16x16x32_bf16(
            Ah[fm], Bl[fn], acc[fm][fn], 0, 0, 0);
        acc[fm][fn] = __builtin_amdgcn_mfma_f32_16x16x32_bf16(
            Al[fm], Bh[fn], acc[fm][fn], 0, 0, 0);
      }
    }
    __syncthreads();
  }

  const int cr = (lane >> 4) * 4;
  const int cc = lane & 15;
#pragma unroll
  for (int fn = 0; fn < 4; ++fn) {
    const int gj = wn * 64 + fn * 16 + cc;
    const float bias = b_ih[gj] + b_hh[gj];
#pragma unroll
    for (int fm = 0; fm < 4; ++fm) {
      const size_t gr = R0 + wm * 64 + fm * 16 + cr;
#pragma unroll
      for (int r = 0; r < 4; ++r) {
        xproj[(gr + r) * G4 + gj] = acc[fm][fn][r] + bias;
      }
    }
  }
}

// ---------------------------------------------------------------------------
// Phase 2: LSTM scan via MFMA broadcast trick (R14) + PERSISTENT ZERO QUAD.
// R14 re-materialized 16 zero acc-quads (64 reg writes, ~150cyc issue) EVERY
// step. Fix: one loop-invariant zq (opaque via empty asm so the backend
// cannot constant-fold it back into per-use zero materialization); each
// tile's first MFMA writes a fresh D from zq: d = mfma(hA0,B0,zq);
// d = mfma(hA1,B1,d). D is fully overwritten by MFMA -> no init needed.
// Everything else identical to R14 (counted-vmcnt x-pipeline, f16 LDS parity
// h-buffer, zero barriers, asm-volatile W pinning + waves_per_eu(1,1)).
// ---------------------------------------------------------------------------
__global__ __attribute__((amdgpu_flat_work_group_size(64, 64)))
__attribute__((amdgpu_waves_per_eu(1, 1))) void lstm_scan_mfma(
    const float* __restrict__ xproj, const _Float16* __restrict__ Whh16,
    float* __restrict__ hT) {
  const int b = blockIdx.x;   // 0..31
  const int l = threadIdx.x;  // lane = unit u
  const int kg8 = (l >> 4) * 8;
  const bool k1 = ((l >> 4) & 1) != 0;
  const bool k2 = ((l >> 4) & 2) != 0;

  __shared__ alignas(16) _Float16 hbuf[2][H_SZ];

  // --- pin B-fragments: 16 tiles x 2 kslices = 32 quads = 128 VGPRs ---
  const _Float16* wb = Whh16 + (size_t)(l & 15) * H_SZ + kg8;
#define PINB(n)                                                               \
  f32x4 wB0_##n, wB1_##n;                                                     \
  {                                                                           \
    const _Float16* a0_##n = wb + (n) * (16 * H_SZ);                          \
    const _Float16* a1_##n = wb + (n) * (16 * H_SZ) + 32;                     \
    asm volatile("global_load_dwordx4 %0, %1, off" : "=v"(wB0_##n) : "v"(a0_##n)); \
    asm volatile("global_load_dwordx4 %0, %1, off" : "=v"(wB1_##n) : "v"(a1_##n)); \
  }
  REP16(PINB)
#undef PINB
  asm volatile("s_waitcnt vmcnt(0)" ::: "memory");

  // persistent zero quad: materialized once; opaque so it stays in registers
  f32x4 zq = {0.f, 0.f, 0.f, 0.f};
  asm volatile("" : "+v"(zq));

  hbuf[0][l] = (_Float16)0.f;
  float c = 0.f, hval = 0.f;
  int p = 0;

  const float* a_next = xproj + (size_t)b * G4 + l;
  const size_t step_off = (size_t)B_SZ * G4;  // floats per t

  float xi0, xf0, xg0, xo0, xi1, xf1, xg1, xo1;
  float xi2, xf2, xg2, xo2, xi3, xf3, xg3, xo3;

#define XLOAD(S, a)                                                     \
  asm volatile("global_load_dword %0, %4, off\n\t"                      \
               "global_load_dword %1, %4, off offset:256\n\t"           \
               "global_load_dword %2, %4, off offset:512\n\t"           \
               "global_load_dword %3, %4, off offset:768"               \
               : "=&v"(xi##S), "=&v"(xf##S), "=&v"(xg##S), "=&v"(xo##S) \
               : "v"(a));

  // prologue: t = 0..3 in flight (16 outstanding)
  XLOAD(0, a_next) a_next += step_off;
  XLOAD(1, a_next) a_next += step_off;
  XLOAD(2, a_next) a_next += step_off;
  XLOAD(3, a_next) a_next += step_off;  // points at t=4

  for (int it = 0; it < T_STEPS / 4; ++it) {
    const int tb = it * 4;

#define TILE(n)                                                               \
    f32x4 acc_##n;                                                            \
    acc_##n = __builtin_amdgcn_mfma_f32_16x16x32_f16(                         \
        hA0, __builtin_bit_cast(f16x8, wB0_##n), zq, 0, 0, 0);                \
    acc_##n = __builtin_amdgcn_mfma_f32_16x16x32_f16(                         \
        hA1, __builtin_bit_cast(f16x8, wB1_##n), acc_##n, 0, 0, 0);

#define SLOT(S)                                                               \
    {                                                                         \
      /* oldest 4 x-loads retire; 12 stay in flight */                        \
      asm volatile("s_waitcnt vmcnt(12)"                                      \
                   : "+v"(xi##S), "+v"(xf##S), "+v"(xg##S), "+v"(xo##S));     \
      /* A fragments: same h quad for every lane in a k-group (broadcast) */  \
      const f16x8 hA0 = *(const f16x8*)&hbuf[p][kg8];                         \
      const f16x8 hA1 = *(const f16x8*)&hbuf[p][32 + kg8];                    \
      REP16(TILE)                                                             \
      /* gate g of unit l: tile g*4+(l>>4), col l&15; rows identical */       \
      const float di = sel4(acc_0[0], acc_1[0], acc_2[0], acc_3[0], k1, k2);  \
      const float df = sel4(acc_4[0], acc_5[0], acc_6[0], acc_7[0], k1, k2);  \
      const float dg = sel4(acc_8[0], acc_9[0], acc_10[0], acc_11[0], k1, k2);\
      const float dq = sel4(acc_12[0], acc_13[0], acc_14[0], acc_15[0], k1, k2);\
      const float pi = xi##S + di;                                            \
      const float pf = xf##S + df;                                            \
      const float pg = xg##S + dg;                                            \
      const float po = xo##S + dq;                                            \
      c = sigm_f(pf) * c + sigm_f(pi) * tanh_f(pg);                           \
      hval = sigm_f(po) * tanh_f(c);                                          \
      hbuf[p ^ 1][l] = (_Float16)hval;                                        \
      p ^= 1;                                                                 \
      /* re-issue set S for t+4 (clamped addr near tail; never consumed) */   \
      XLOAD(S, a_next)                                                        \
      if (tb + (S) + 4 < T_STEPS - 1) a_next += step_off;                     \
    }

    SLOT(0)
    SLOT(1)
    SLOT(2)
    SLOT(3)

#undef SLOT
#undef TILE
  }
#undef XLOAD

  hT[b * H_SZ + l] = hval;
}

// ---------------------------------------------------------------------------
// Phase 3: out[b][c] = sum_k hT[b][k] * W_lin[c][k] + b_lin[c]
// ---------------------------------------------------------------------------
__global__ __launch_bounds__(128) void final_linear_kernel(
    const float* __restrict__ hT, const float* __restrict__ W_lin,
    const float* __restrict__ b_lin, float* __restrict__ out) {
  const int b = blockIdx.x;
  const int cc = threadIdx.x;

  __shared__ float h_l[H_SZ];
  if (threadIdx.x < H_SZ) h_l[threadIdx.x] = hT[b * H_SZ + threadIdx.x];
  __syncthreads();

  if (cc < C_SZ) {
    float acc = b_lin[cc];
    const float* wr = W_lin + (size_t)cc * H_SZ;
#pragma unroll
    for (int k = 0; k < H_SZ; ++k) acc += h_l[k] * wr[k];
    out[b * C_SZ + cc] = acc;
  }
}

// ---------------------------------------------------------------------------
extern "C" void kernel_launch(void* const* d_in, const int* in_sizes, int n_in,
                              void* d_out, int out_size, void* d_ws,
                              size_t ws_size, hipStream_t stream) {
  const float* x = (const float*)d_in[0];      // [T,B,F]
  const float* W_ih = (const float*)d_in[1];   // [4H,F]
  const float* W_hh = (const float*)d_in[2];   // [4H,H]
  const float* b_ih = (const float*)d_in[3];   // [4H]
  const float* b_hh = (const float*)d_in[4];   // [4H]
  const float* W_lin = (const float*)d_in[5];  // [C,H]
  const float* b_lin = (const float*)d_in[6];  // [C]
  float* out = (float*)d_out;                  // [B,C]

  // ws layout: xproj 32MB | hT 8KB | Whi 1MB | Wlo 1MB | Whh_f16 32KB
  const size_t XP_BYTES = (size_t)T_STEPS * B_SZ * G4 * sizeof(float);
  float* xproj = (float*)d_ws;
  float* hT = (float*)((char*)d_ws + XP_BYTES);
  unsigned short* Whi_g = (unsigned short*)((char*)d_ws + XP_BYTES + 8192);
  unsigned short* Wlo_g = Whi_g + (size_t)G4 * F_SZ;
  _Float16* Whh16 = (_Float16*)(Wlo_g + (size_t)G4 * F_SZ);

  presplit_w<<<512, 256, 0, stream>>>(W_ih, Whi_g, Wlo_g);
  whh_to_f16<<<16, 256, 0, stream>>>(W_hh, Whh16);
  xproj_mfma<<<(T_STEPS * B_SZ) / BM, 512, 0, stream>>>(x, Whi_g, Wlo_g, b_ih,
                                                        b_hh, xproj);
  lstm_scan_mfma<<<B_SZ, 64, 0, stream>>>(xproj, Whh16, hT);
  final_linear_kernel<<<B_SZ, 128, 0, stream>>>(hT, W_lin, b_lin, out);
}